// Round 9
// baseline (1038.133 us; speedup 1.0000x reference)
//
#include <hip/hip_runtime.h>
#include <hip/hip_bf16.h>
#include <cstdint>
#include <cstddef>

typedef unsigned short ushort_t;
typedef __bf16 bf16x8 __attribute__((ext_vector_type(8)));
typedef float floatx4 __attribute__((ext_vector_type(4)));

#define S_LEN 2048
#define DIN   512
#define DH    512
#define NHEAD 8
#define NBAT  4
#define NBH   32
#define HP    4096   // NHEAD*DH

// ---------- static device workspace ----------
#define MiB (1024ull * 1024ull)
#define WQT_OFF   (0ull)           //  4 MiB  WqT [8][512e][512d] bf16
#define WKT_OFF   (4ull  * MiB)    //  4 MiB
#define WVT_OFF   (8ull  * MiB)    //  4 MiB
#define WPT_OFF   (12ull * MiB)    //  4 MiB  WpT [512][4096] bf16
#define XBF_OFF   (16ull * MiB)    //  8 MiB  x bf16 [4][2048][512]
#define Q_OFF     (24ull * MiB)    // 64 MiB  [32][2048][512] bf16
#define K_OFF     (88ull * MiB)    // 64 MiB
#define VT_OFF    (152ull * MiB)   // 64 MiB  [32][512][2048] bf16
#define O_OFF     (216ull * MiB)   // 64 MiB  [4][2048][4096] bf16 (cat)
#define LSUM_OFF  (280ull * MiB)   // 64 KiB  fp32 [8][2048]
#define P_OFF     (281ull * MiB)   // 64 MiB  [8][2048][2048] bf16
#define WS_BYTES  (346ull * MiB)

__device__ __align__(256) unsigned char g_ws[WS_BYTES];

// ---------- helpers ----------
__device__ __forceinline__ ushort_t f2bf(float f) {
  union { float f; uint32_t u; } v; v.f = f;
  uint32_t r = v.u + 0x7fffu + ((v.u >> 16) & 1u);
  return (ushort_t)(r >> 16);
}

typedef __attribute__((address_space(3))) uint32_t lds_uint;
typedef __attribute__((address_space(1))) const uint32_t glb_uint;

__device__ __forceinline__ void async16(void* lds, const void* g) {
  __builtin_amdgcn_global_load_lds((glb_uint*)g, (lds_uint*)lds, 16, 0, 0);
}

// ---------- GEMM core: C[128x128] = A[128xK] * Bt[128xK]^T, bf16, fp32 acc ----
// block = 256 threads (4 waves, 2x2), each wave 64x64 via 4x4 16x16x32 MFMAs.
// m97-style staging: global_load_lds width=16, 2-barrier K-loop.
// LDS dest check: wave w lane l lands at byte w*1024 + l*16 == row-major
// [128][32] offset of row w*16+(l>>2), cols (l&3)*8 (thread t=w*64+l stages
// rows t>>2 and t>>2+64, cols (t&3)*8..+8).
__device__ __forceinline__ void gemm_core(
    const ushort_t* __restrict__ A, const ushort_t* __restrict__ Bt,
    int lda, int ldb, int kdim,
    ushort_t* As, ushort_t* Bs, floatx4 acc[4][4])
{
  const int t = threadIdx.x;
  const int w = t >> 6;
  const int l = t & 63;
  const int wrow = w >> 1, wcol = w & 1;
  const int l15 = l & 15, lq = l >> 4;

  const ushort_t* gA = A + (size_t)(t >> 2) * lda + (t & 3) * 8;
  const ushort_t* gB = Bt + (size_t)(t >> 2) * ldb + (t & 3) * 8;
  char* ldsA = (char*)As + w * 1024;   // wave-uniform LDS base
  char* ldsB = (char*)Bs + w * 1024;
  const size_t strideA = (size_t)64 * lda;
  const size_t strideB = (size_t)64 * ldb;

  const ushort_t* rdA = As + (wrow * 64 + l15) * 32 + lq * 8;
  const ushort_t* rdB = Bs + (wcol * 64 + l15) * 32 + lq * 8;

#pragma unroll
  for (int i = 0; i < 4; ++i)
#pragma unroll
    for (int j = 0; j < 4; ++j)
      acc[i][j] = (floatx4){0.f, 0.f, 0.f, 0.f};

#pragma unroll 1
  for (int k0 = 0; k0 < kdim; k0 += 32) {
    async16(ldsA,        gA);
    async16(ldsA + 4096, gA + strideA);   // rows 64..127
    async16(ldsB,        gB);
    async16(ldsB + 4096, gB + strideB);
    gA += 32; gB += 32;
    __syncthreads();   // drains vmcnt (global_load_lds) + prior LDS readers

    bf16x8 af[4], bfr[4];
#pragma unroll
    for (int i = 0; i < 4; ++i) af[i] = *(const bf16x8*)(rdA + i * 512);
#pragma unroll
    for (int j = 0; j < 4; ++j) bfr[j] = *(const bf16x8*)(rdB + j * 512);
#pragma unroll
    for (int i = 0; i < 4; ++i)
#pragma unroll
      for (int j = 0; j < 4; ++j)
        acc[i][j] = __builtin_amdgcn_mfma_f32_16x16x32_bf16(af[i], bfr[j], acc[i][j], 0, 0, 0);
    __syncthreads();   // readers done before next iter's staging overwrites
  }
}

// ---------- fp32 -> bf16 bulk convert into g_ws ----------
__global__ __launch_bounds__(256) void convert_f32_bf16(
    const float* __restrict__ src, size_t dstOff, int n)
{
  ushort_t* dst = (ushort_t*)(g_ws + dstOff);
  int i = (blockIdx.x * 256 + threadIdx.x) * 4;
  if (i >= n) return;
  float4 v = *(const float4*)(src + i);
  ushort_t o[4] = {f2bf(v.x), f2bf(v.y), f2bf(v.z), f2bf(v.w)};
  *(uint2*)(dst + i) = *(const uint2*)o;
}

// ---------- fp32 [R][C] -> bf16 [C][R] transpose into g_ws, batched over z ----
__global__ __launch_bounds__(256) void transpose_f32_bf16(
    const float* __restrict__ src, size_t dstOff, int R, int C)
{
  __shared__ ushort_t tile[32][33];
  ushort_t* dst = (ushort_t*)(g_ws + dstOff) + (size_t)blockIdx.z * R * C;
  src += (size_t)blockIdx.z * R * C;
  int r0 = blockIdx.y * 32, c0 = blockIdx.x * 32;
  int tx = threadIdx.x & 31, ty = threadIdx.x >> 5;
  for (int i = ty; i < 32; i += 8)
    tile[i][tx] = f2bf(src[(size_t)(r0 + i) * C + (c0 + tx)]);
  __syncthreads();
  for (int i = ty; i < 32; i += 8)
    dst[(size_t)(c0 + i) * R + (r0 + tx)] = tile[tx][i];
}

// ---------- QKV projection, all batches/heads: z in [0,96) ----------
__global__ __launch_bounds__(256) void qkv_gemm(
    const float* __restrict__ bq, const float* __restrict__ bk,
    const float* __restrict__ bv)
{
  __shared__ __align__(16) ushort_t As[128 * 32], Bs[128 * 32];
  const int z = blockIdx.z;
  const int bh = z & 31, qkv = z >> 5, b = bh >> 3, h = bh & 7;
  const size_t wOff = (qkv == 0) ? WQT_OFF : (qkv == 1) ? WKT_OFF : WVT_OFF;
  const float* bias = ((qkv == 0) ? bq : (qkv == 1) ? bk : bv) + h * DH;
  const int tileM = blockIdx.y * 128, tileN = blockIdx.x * 128;

  const ushort_t* A  = (const ushort_t*)(g_ws + XBF_OFF)
                       + ((size_t)b * S_LEN + tileM) * DIN;
  const ushort_t* Bt = (const ushort_t*)(g_ws + wOff)
                       + ((size_t)h * DH + tileN) * DIN;
  floatx4 acc[4][4];
  gemm_core(A, Bt, DIN, DIN, DIN, As, Bs, acc);

  ushort_t* Qb = (ushort_t*)(g_ws + Q_OFF);
  ushort_t* Kb = (ushort_t*)(g_ws + K_OFF);
  ushort_t* VT = (ushort_t*)(g_ws + VT_OFF);
  const int t = threadIdx.x, w = t >> 6, l = t & 63;
  const int wrow = w >> 1, wcol = w & 1, l15 = l & 15, lq = l >> 4;
#pragma unroll
  for (int j = 0; j < 4; ++j) {
    const int n = tileN + wcol * 64 + j * 16 + l15;
    const float bsn = bias[n];
#pragma unroll
    for (int i = 0; i < 4; ++i) {
#pragma unroll
      for (int r = 0; r < 4; ++r) {
        const int m = tileM + wrow * 64 + i * 16 + lq * 4 + r;
        const float v = acc[i][j][r] + bsn;
        if (qkv == 0)      Qb[((size_t)bh * S_LEN + m) * DH + n] = f2bf(v);
        else if (qkv == 1) Kb[((size_t)bh * S_LEN + m) * DH + n] = f2bf(v);
        else               VT[((size_t)bh * DH + n) * S_LEN + m] = f2bf(v);
      }
    }
  }
}

// ---------- scores + masked exp for head chunk [c0, c0+8) ----------
__global__ __launch_bounds__(256) void scores_kernel(
    const int* __restrict__ mask, int c0)
{
  __shared__ __align__(16) ushort_t As[128 * 32], Bs[128 * 32];
  const int hl = blockIdx.z, bh = c0 + hl, b = bh >> 3;
  const int tileM = blockIdx.y * 128, tileN = blockIdx.x * 128;

  const ushort_t* A  = (const ushort_t*)(g_ws + Q_OFF)
                       + ((size_t)bh * S_LEN + tileM) * DH;
  const ushort_t* Bt = (const ushort_t*)(g_ws + K_OFF)
                       + ((size_t)bh * S_LEN + tileN) * DH;
  floatx4 acc[4][4];
  gemm_core(A, Bt, DH, DH, DH, As, Bs, acc);

  const float scale = 0.04419417382415922f;  // 1/sqrt(512)
  const int t = threadIdx.x, w = t >> 6, l = t & 63;
  const int wrow = w >> 1, wcol = w & 1, l15 = l & 15, lq = l >> 4;
  ushort_t* Pp = (ushort_t*)(g_ws + P_OFF) + (size_t)hl * S_LEN * S_LEN;
  const int* mask_b = mask + (size_t)b * S_LEN;

#pragma unroll
  for (int j = 0; j < 4; ++j) {
    const int n = tileN + wcol * 64 + j * 16 + l15;
    const int mv = mask_b[n];
#pragma unroll
    for (int i = 0; i < 4; ++i) {
#pragma unroll
      for (int r = 0; r < 4; ++r) {
        const int m = tileM + wrow * 64 + i * 16 + lq * 4 + r;
        float s = fminf(acc[i][j][r] * scale, 30.f);  // clamp: no inf possible
        const float p = mv ? __expf(s) : 0.f;
        Pp[(size_t)m * S_LEN + n] = f2bf(p);
      }
    }
  }
}

// ---------- row sums of P chunk (deterministic, no atomics) ----------
__global__ __launch_bounds__(256) void rowsum_kernel()
{
  const int w = threadIdx.x >> 6, l = threadIdx.x & 63;
  const int row = blockIdx.x * 4 + w;
  const int hl = blockIdx.y;
  const ushort_t* Pr = (const ushort_t*)(g_ws + P_OFF)
                       + (size_t)hl * S_LEN * S_LEN + (size_t)row * S_LEN;
  float* lsum = (float*)(g_ws + LSUM_OFF);

  float s = 0.f;
#pragma unroll
  for (int kk = 0; kk < 4; ++kk) {
    bf16x8 v = *(const bf16x8*)(Pr + kk * 512 + l * 8);
#pragma unroll
    for (int e = 0; e < 8; ++e) s += (float)v[e];
  }
  s += __shfl_xor(s, 1);
  s += __shfl_xor(s, 2);
  s += __shfl_xor(s, 4);
  s += __shfl_xor(s, 8);
  s += __shfl_xor(s, 16);
  s += __shfl_xor(s, 32);
  if (l == 0) lsum[(size_t)hl * S_LEN + row] = s;
}

// ---------- P*V, divide by rowsum, store cat-layout O ----------
__global__ __launch_bounds__(256) void pv_kernel(int c0)
{
  __shared__ __align__(16) ushort_t As[128 * 32], Bs[128 * 32];
  const int hl = blockIdx.z, bh = c0 + hl, b = bh >> 3, h = bh & 7;
  const int tileM = blockIdx.y * 128, tileN = blockIdx.x * 128;

  const ushort_t* A  = (const ushort_t*)(g_ws + P_OFF)
                       + (size_t)hl * S_LEN * S_LEN + (size_t)tileM * S_LEN;
  const ushort_t* Bt = (const ushort_t*)(g_ws + VT_OFF)
                       + ((size_t)bh * DH + tileN) * S_LEN;
  floatx4 acc[4][4];
  gemm_core(A, Bt, S_LEN, S_LEN, S_LEN, As, Bs, acc);

  const float* lsum = (const float*)(g_ws + LSUM_OFF);
  ushort_t* Ob = (ushort_t*)(g_ws + O_OFF);
  const int t = threadIdx.x, w = t >> 6, l = t & 63;
  const int wrow = w >> 1, wcol = w & 1, l15 = l & 15, lq = l >> 4;
#pragma unroll
  for (int i = 0; i < 4; ++i) {
#pragma unroll
    for (int r = 0; r < 4; ++r) {
      const int m = tileM + wrow * 64 + i * 16 + lq * 4 + r;
      const float lv = lsum[(size_t)hl * S_LEN + m];
      const float inv = (lv > 1e-20f) ? 1.0f / lv : 0.f;  // no inf possible
#pragma unroll
      for (int j = 0; j < 4; ++j) {
        const int n = tileN + wcol * 64 + j * 16 + l15;
        Ob[((size_t)b * S_LEN + m) * HP + h * DH + n] = f2bf(acc[i][j][r] * inv);
      }
    }
  }
}

// ---------- out projection: out_f32[8192][512] = Ob[8192][4096]*WpT^T + bp ----
__global__ __launch_bounds__(256) void proj_kernel(
    const float* __restrict__ bp, float* __restrict__ out)
{
  __shared__ __align__(16) ushort_t As[128 * 32], Bs[128 * 32];
  const int tileM = blockIdx.y * 128, tileN = blockIdx.x * 128;

  const ushort_t* A  = (const ushort_t*)(g_ws + O_OFF) + (size_t)tileM * HP;
  const ushort_t* Bt = (const ushort_t*)(g_ws + WPT_OFF) + (size_t)tileN * HP;
  floatx4 acc[4][4];
  gemm_core(A, Bt, HP, HP, HP, As, Bs, acc);

  const int t = threadIdx.x, w = t >> 6, l = t & 63;
  const int wrow = w >> 1, wcol = w & 1, l15 = l & 15, lq = l >> 4;
#pragma unroll
  for (int j = 0; j < 4; ++j) {
    const int n = tileN + wcol * 64 + j * 16 + l15;
    const float bsn = bp[n];
#pragma unroll
    for (int i = 0; i < 4; ++i) {
#pragma unroll
      for (int r = 0; r < 4; ++r) {
        const int m = tileM + wrow * 64 + i * 16 + lq * 4 + r;
        out[(size_t)m * DH + n] = acc[i][j][r] + bsn;   // fp32 store
      }
    }
  }
}

// ---------- host ----------
extern "C" void kernel_launch(void* const* d_in, const int* in_sizes, int n_in,
                              void* d_out, int out_size, void* d_ws, size_t ws_size,
                              hipStream_t stream) {
  // Inputs fp32 (mask int32); OUTPUT fp32.
  const float* x  = (const float*)d_in[0];
  const int*   msk= (const int*)d_in[1];
  const float* Wq = (const float*)d_in[2];
  const float* bq = (const float*)d_in[3];
  const float* Wk = (const float*)d_in[4];
  const float* bk = (const float*)d_in[5];
  const float* Wv = (const float*)d_in[6];
  const float* bv = (const float*)d_in[7];
  const float* Wp = (const float*)d_in[8];
  const float* bp = (const float*)d_in[9];
  float* out = (float*)d_out;

  // x -> bf16 (all batches)
  convert_f32_bf16<<<dim3(NBAT * S_LEN * DIN / 1024), 256, 0, stream>>>(
      x, XBF_OFF, NBAT * S_LEN * DIN);

  // weight transposes (fp32 -> bf16)
  transpose_f32_bf16<<<dim3(16, 16, NHEAD), 256, 0, stream>>>(Wq, WQT_OFF, DIN, DH);
  transpose_f32_bf16<<<dim3(16, 16, NHEAD), 256, 0, stream>>>(Wk, WKT_OFF, DIN, DH);
  transpose_f32_bf16<<<dim3(16, 16, NHEAD), 256, 0, stream>>>(Wv, WVT_OFF, DIN, DH);
  transpose_f32_bf16<<<dim3(16, 128, 1),    256, 0, stream>>>(Wp, WPT_OFF, HP, DH);

  // Q/K/V^T for all 32 (b,h)
  qkv_gemm<<<dim3(DH / 128, S_LEN / 128, 3 * NBH), 256, 0, stream>>>(bq, bk, bv);

  // attention in chunks of 8 heads (P chunk = 64 MiB, partly L3-resident)
  for (int c0 = 0; c0 < NBH; c0 += 8) {
    scores_kernel<<<dim3(S_LEN / 128, S_LEN / 128, 8), 256, 0, stream>>>(msk, c0);
    rowsum_kernel<<<dim3(S_LEN / 4, 8), 256, 0, stream>>>();
    pv_kernel<<<dim3(DH / 128, S_LEN / 128, 8), 256, 0, stream>>>(c0);
  }

  // final projection (fp32 out)
  proj_kernel<<<dim3(DH / 128, (NBAT * S_LEN) / 128), 256, 0, stream>>>(bp, out);
}

// Round 10
// 1016.207 us; speedup vs baseline: 1.0216x; 1.0216x over previous
//
#include <hip/hip_runtime.h>
#include <hip/hip_bf16.h>
#include <cstdint>
#include <cstddef>

typedef unsigned short ushort_t;
typedef __bf16 bf16x8 __attribute__((ext_vector_type(8)));
typedef float floatx4 __attribute__((ext_vector_type(4)));

#define S_LEN 2048
#define DIN   512
#define DH    512
#define NHEAD 8
#define NBAT  4
#define NBH   32
#define HP    4096   // NHEAD*DH

// ---------- static device workspace ----------
#define MiB (1024ull * 1024ull)
#define WQT_OFF   (0ull)           //  4 MiB  WqT [8][512e][512d] bf16
#define WKT_OFF   (4ull  * MiB)    //  4 MiB
#define WVT_OFF   (8ull  * MiB)    //  4 MiB
#define WPT_OFF   (12ull * MiB)    //  4 MiB  WpT [512][4096] bf16
#define XBF_OFF   (16ull * MiB)    //  8 MiB  x bf16 [4][2048][512]
#define Q_OFF     (24ull * MiB)    // 64 MiB  [32][2048][512] bf16
#define K_OFF     (88ull * MiB)    // 64 MiB
#define VT_OFF    (152ull * MiB)   // 64 MiB  [32][512][2048] bf16
#define O_OFF     (216ull * MiB)   // 64 MiB  [4][2048][4096] bf16 (cat)
#define LSUM_OFF  (280ull * MiB)   // 64 KiB  fp32 [8][2048]
#define P_OFF     (281ull * MiB)   // 64 MiB  [8][2048][2048] bf16
#define WS_BYTES  (346ull * MiB)

__device__ __align__(256) unsigned char g_ws[WS_BYTES];

// ---------- helpers ----------
__device__ __forceinline__ ushort_t f2bf(float f) {
  union { float f; uint32_t u; } v; v.f = f;
  uint32_t r = v.u + 0x7fffu + ((v.u >> 16) & 1u);
  return (ushort_t)(r >> 16);
}

typedef __attribute__((address_space(3))) uint32_t lds_uint;
typedef __attribute__((address_space(1))) const uint32_t glb_uint;

__device__ __forceinline__ void async16(void* lds, const void* g) {
  __builtin_amdgcn_global_load_lds((glb_uint*)g, (lds_uint*)lds, 16, 0, 0);
}

// ---------- GEMM core: C[128x128] = A[128xK] * Bt[128xK]^T, bf16, fp32 acc ----
// block = 256 threads (4 waves, 2x2), each wave 64x64 via 4x4 16x16x32 MFMAs.
// BK=64 K-windows: 8 async16/thread -> barrier -> 2x(8 ds_read_b128 + 16 MFMA)
// -> barrier. Halves barrier/drain count vs BK=32.
// Staging map: chunk id = q*256 + t (q=0..3) -> row q*32+(t>>3), col (t&7)*8;
// LDS byte = q*4096 + w*1024 + l*16 (wave-uniform base per issue).
__device__ __forceinline__ void gemm_core(
    const ushort_t* __restrict__ A, const ushort_t* __restrict__ Bt,
    int lda, int ldb, int kdim,
    ushort_t* As, ushort_t* Bs, floatx4 acc[4][4])
{
  const int t = threadIdx.x;
  const int w = t >> 6;
  const int l = t & 63;
  const int wrow = w >> 1, wcol = w & 1;
  const int l15 = l & 15, lq = l >> 4;

  const ushort_t* gA = A + (size_t)(t >> 3) * lda + (t & 7) * 8;
  const ushort_t* gB = Bt + (size_t)(t >> 3) * ldb + (t & 7) * 8;
  char* ldsA = (char*)As + w * 1024;   // wave-uniform LDS base
  char* ldsB = (char*)Bs + w * 1024;
  const size_t strideA = (size_t)32 * lda;   // 32 rows per q-step
  const size_t strideB = (size_t)32 * ldb;

  // readers: LDS row-major [128][64]
  const ushort_t* rdA = As + (wrow * 64 + l15) * 64 + lq * 8;
  const ushort_t* rdB = Bs + (wcol * 64 + l15) * 64 + lq * 8;

#pragma unroll
  for (int i = 0; i < 4; ++i)
#pragma unroll
    for (int j = 0; j < 4; ++j)
      acc[i][j] = (floatx4){0.f, 0.f, 0.f, 0.f};

#pragma unroll 1
  for (int k0 = 0; k0 < kdim; k0 += 64) {
#pragma unroll
    for (int q = 0; q < 4; ++q) {
      async16(ldsA + q * 4096, gA + q * strideA);
      async16(ldsB + q * 4096, gB + q * strideB);
    }
    gA += 64; gB += 64;
    __syncthreads();   // drains global_load_lds + prior LDS readers

#pragma unroll
    for (int ks = 0; ks < 2; ++ks) {
      bf16x8 af[4], bfr[4];
#pragma unroll
      for (int i = 0; i < 4; ++i) af[i] = *(const bf16x8*)(rdA + i * 1024 + ks * 32);
#pragma unroll
      for (int j = 0; j < 4; ++j) bfr[j] = *(const bf16x8*)(rdB + j * 1024 + ks * 32);
#pragma unroll
      for (int i = 0; i < 4; ++i)
#pragma unroll
        for (int j = 0; j < 4; ++j)
          acc[i][j] = __builtin_amdgcn_mfma_f32_16x16x32_bf16(af[i], bfr[j], acc[i][j], 0, 0, 0);
    }
    __syncthreads();   // readers done before next window's staging
  }
}

// ---------- fp32 -> bf16 bulk convert into g_ws ----------
__global__ __launch_bounds__(256) void convert_f32_bf16(
    const float* __restrict__ src, size_t dstOff, int n)
{
  ushort_t* dst = (ushort_t*)(g_ws + dstOff);
  int i = (blockIdx.x * 256 + threadIdx.x) * 4;
  if (i >= n) return;
  float4 v = *(const float4*)(src + i);
  ushort_t o[4] = {f2bf(v.x), f2bf(v.y), f2bf(v.z), f2bf(v.w)};
  *(uint2*)(dst + i) = *(const uint2*)o;
}

// ---------- fp32 [R][C] -> bf16 [C][R] transpose into g_ws, batched over z ----
__global__ __launch_bounds__(256) void transpose_f32_bf16(
    const float* __restrict__ src, size_t dstOff, int R, int C)
{
  __shared__ ushort_t tile[32][33];
  ushort_t* dst = (ushort_t*)(g_ws + dstOff) + (size_t)blockIdx.z * R * C;
  src += (size_t)blockIdx.z * R * C;
  int r0 = blockIdx.y * 32, c0 = blockIdx.x * 32;
  int tx = threadIdx.x & 31, ty = threadIdx.x >> 5;
  for (int i = ty; i < 32; i += 8)
    tile[i][tx] = f2bf(src[(size_t)(r0 + i) * C + (c0 + tx)]);
  __syncthreads();
  for (int i = ty; i < 32; i += 8)
    dst[(size_t)(c0 + i) * R + (r0 + tx)] = tile[tx][i];
}

// ---------- zero lsum (64 KiB) ----------
__global__ __launch_bounds__(256) void zero_lsum()
{
  float* lsum = (float*)(g_ws + LSUM_OFF);
  int i = (blockIdx.x * 256 + threadIdx.x) * 4;
  *(float4*)(lsum + i) = (float4){0.f, 0.f, 0.f, 0.f};
}

// ---------- QKV projection, all batches/heads: z in [0,96) ----------
__global__ __launch_bounds__(256) void qkv_gemm(
    const float* __restrict__ bq, const float* __restrict__ bk,
    const float* __restrict__ bv)
{
  __shared__ __align__(16) ushort_t As[128 * 64], Bs[128 * 64];
  const int z = blockIdx.z;
  const int bh = z & 31, qkv = z >> 5, b = bh >> 3, h = bh & 7;
  const size_t wOff = (qkv == 0) ? WQT_OFF : (qkv == 1) ? WKT_OFF : WVT_OFF;
  const float* bias = ((qkv == 0) ? bq : (qkv == 1) ? bk : bv) + h * DH;
  const int tileM = blockIdx.y * 128, tileN = blockIdx.x * 128;

  const ushort_t* A  = (const ushort_t*)(g_ws + XBF_OFF)
                       + ((size_t)b * S_LEN + tileM) * DIN;
  const ushort_t* Bt = (const ushort_t*)(g_ws + wOff)
                       + ((size_t)h * DH + tileN) * DIN;
  floatx4 acc[4][4];
  gemm_core(A, Bt, DIN, DIN, DIN, As, Bs, acc);

  ushort_t* Qb = (ushort_t*)(g_ws + Q_OFF);
  ushort_t* Kb = (ushort_t*)(g_ws + K_OFF);
  ushort_t* VT = (ushort_t*)(g_ws + VT_OFF);
  const int t = threadIdx.x, w = t >> 6, l = t & 63;
  const int wrow = w >> 1, wcol = w & 1, l15 = l & 15, lq = l >> 4;
#pragma unroll
  for (int j = 0; j < 4; ++j) {
    const int n = tileN + wcol * 64 + j * 16 + l15;
    const float bsn = bias[n];
#pragma unroll
    for (int i = 0; i < 4; ++i) {
#pragma unroll
      for (int r = 0; r < 4; ++r) {
        const int m = tileM + wrow * 64 + i * 16 + lq * 4 + r;
        const float v = acc[i][j][r] + bsn;
        if (qkv == 0)      Qb[((size_t)bh * S_LEN + m) * DH + n] = f2bf(v);
        else if (qkv == 1) Kb[((size_t)bh * S_LEN + m) * DH + n] = f2bf(v);
        else               VT[((size_t)bh * DH + n) * S_LEN + m] = f2bf(v);
      }
    }
  }
}

// ---------- scores + masked exp + fused row-sum for head chunk [c0, c0+8) ----
__global__ __launch_bounds__(256) void scores_kernel(
    const int* __restrict__ mask, int c0)
{
  __shared__ __align__(16) ushort_t As[128 * 64], Bs[128 * 64];
  const int hl = blockIdx.z, bh = c0 + hl, b = bh >> 3;
  const int tileM = blockIdx.y * 128, tileN = blockIdx.x * 128;

  const ushort_t* A  = (const ushort_t*)(g_ws + Q_OFF)
                       + ((size_t)bh * S_LEN + tileM) * DH;
  const ushort_t* Bt = (const ushort_t*)(g_ws + K_OFF)
                       + ((size_t)bh * S_LEN + tileN) * DH;
  floatx4 acc[4][4];
  gemm_core(A, Bt, DH, DH, DH, As, Bs, acc);

  const float scale = 0.04419417382415922f;  // 1/sqrt(512)
  const int t = threadIdx.x, w = t >> 6, l = t & 63;
  const int wrow = w >> 1, wcol = w & 1, l15 = l & 15, lq = l >> 4;
  ushort_t* Pp = (ushort_t*)(g_ws + P_OFF) + (size_t)hl * S_LEN * S_LEN;
  const int* mask_b = mask + (size_t)b * S_LEN;
  float* lsum = (float*)(g_ws + LSUM_OFF);

  float rsum[4][4];
#pragma unroll
  for (int i = 0; i < 4; ++i)
#pragma unroll
    for (int r = 0; r < 4; ++r) rsum[i][r] = 0.f;

#pragma unroll
  for (int j = 0; j < 4; ++j) {
    const int n = tileN + wcol * 64 + j * 16 + l15;
    const int mv = mask_b[n];
#pragma unroll
    for (int i = 0; i < 4; ++i) {
#pragma unroll
      for (int r = 0; r < 4; ++r) {
        const int m = tileM + wrow * 64 + i * 16 + lq * 4 + r;
        float s = fminf(acc[i][j][r] * scale, 30.f);  // clamp: no inf possible
        const float p = mv ? __expf(s) : 0.f;
        rsum[i][r] += p;
        Pp[(size_t)m * S_LEN + n] = f2bf(p);
      }
    }
  }
  // reduce across the 16 lanes sharing each row, one atomic per (row, wave)
#pragma unroll
  for (int i = 0; i < 4; ++i) {
#pragma unroll
    for (int r = 0; r < 4; ++r) {
      float v = rsum[i][r];
      v += __shfl_xor(v, 1);
      v += __shfl_xor(v, 2);
      v += __shfl_xor(v, 4);
      v += __shfl_xor(v, 8);
      if (l15 == 0) {
        const int m = tileM + wrow * 64 + i * 16 + lq * 4 + r;
        atomicAdd(&lsum[(size_t)hl * S_LEN + m], v);
      }
    }
  }
}

// ---------- P*V, divide by rowsum, store cat-layout O ----------
__global__ __launch_bounds__(256) void pv_kernel(int c0)
{
  __shared__ __align__(16) ushort_t As[128 * 64], Bs[128 * 64];
  const int hl = blockIdx.z, bh = c0 + hl, b = bh >> 3, h = bh & 7;
  const int tileM = blockIdx.y * 128, tileN = blockIdx.x * 128;

  const ushort_t* A  = (const ushort_t*)(g_ws + P_OFF)
                       + (size_t)hl * S_LEN * S_LEN + (size_t)tileM * S_LEN;
  const ushort_t* Bt = (const ushort_t*)(g_ws + VT_OFF)
                       + ((size_t)bh * DH + tileN) * S_LEN;
  floatx4 acc[4][4];
  gemm_core(A, Bt, S_LEN, S_LEN, S_LEN, As, Bs, acc);

  const float* lsum = (const float*)(g_ws + LSUM_OFF);
  ushort_t* Ob = (ushort_t*)(g_ws + O_OFF);
  const int t = threadIdx.x, w = t >> 6, l = t & 63;
  const int wrow = w >> 1, wcol = w & 1, l15 = l & 15, lq = l >> 4;
#pragma unroll
  for (int i = 0; i < 4; ++i) {
#pragma unroll
    for (int r = 0; r < 4; ++r) {
      const int m = tileM + wrow * 64 + i * 16 + lq * 4 + r;
      const float lv = lsum[(size_t)hl * S_LEN + m];
      const float inv = (lv > 1e-20f) ? 1.0f / lv : 0.f;  // no inf possible
#pragma unroll
      for (int j = 0; j < 4; ++j) {
        const int n = tileN + wcol * 64 + j * 16 + l15;
        Ob[((size_t)b * S_LEN + m) * HP + h * DH + n] = f2bf(acc[i][j][r] * inv);
      }
    }
  }
}

// ---------- out projection: out_f32[8192][512] = Ob[8192][4096]*WpT^T + bp ----
__global__ __launch_bounds__(256) void proj_kernel(
    const float* __restrict__ bp, float* __restrict__ out)
{
  __shared__ __align__(16) ushort_t As[128 * 64], Bs[128 * 64];
  const int tileM = blockIdx.y * 128, tileN = blockIdx.x * 128;

  const ushort_t* A  = (const ushort_t*)(g_ws + O_OFF) + (size_t)tileM * HP;
  const ushort_t* Bt = (const ushort_t*)(g_ws + WPT_OFF) + (size_t)tileN * HP;
  floatx4 acc[4][4];
  gemm_core(A, Bt, HP, HP, HP, As, Bs, acc);

  const int t = threadIdx.x, w = t >> 6, l = t & 63;
  const int wrow = w >> 1, wcol = w & 1, l15 = l & 15, lq = l >> 4;
#pragma unroll
  for (int j = 0; j < 4; ++j) {
    const int n = tileN + wcol * 64 + j * 16 + l15;
    const float bsn = bp[n];
#pragma unroll
    for (int i = 0; i < 4; ++i) {
#pragma unroll
      for (int r = 0; r < 4; ++r) {
        const int m = tileM + wrow * 64 + i * 16 + lq * 4 + r;
        out[(size_t)m * DH + n] = acc[i][j][r] + bsn;   // fp32 store
      }
    }
  }
}

// ---------- host ----------
extern "C" void kernel_launch(void* const* d_in, const int* in_sizes, int n_in,
                              void* d_out, int out_size, void* d_ws, size_t ws_size,
                              hipStream_t stream) {
  // Inputs fp32 (mask int32); OUTPUT fp32.
  const float* x  = (const float*)d_in[0];
  const int*   msk= (const int*)d_in[1];
  const float* Wq = (const float*)d_in[2];
  const float* bq = (const float*)d_in[3];
  const float* Wk = (const float*)d_in[4];
  const float* bk = (const float*)d_in[5];
  const float* Wv = (const float*)d_in[6];
  const float* bv = (const float*)d_in[7];
  const float* Wp = (const float*)d_in[8];
  const float* bp = (const float*)d_in[9];
  float* out = (float*)d_out;

  // x -> bf16 (all batches)
  convert_f32_bf16<<<dim3(NBAT * S_LEN * DIN / 1024), 256, 0, stream>>>(
      x, XBF_OFF, NBAT * S_LEN * DIN);

  // weight transposes (fp32 -> bf16)
  transpose_f32_bf16<<<dim3(16, 16, NHEAD), 256, 0, stream>>>(Wq, WQT_OFF, DIN, DH);
  transpose_f32_bf16<<<dim3(16, 16, NHEAD), 256, 0, stream>>>(Wk, WKT_OFF, DIN, DH);
  transpose_f32_bf16<<<dim3(16, 16, NHEAD), 256, 0, stream>>>(Wv, WVT_OFF, DIN, DH);
  transpose_f32_bf16<<<dim3(16, 128, 1),    256, 0, stream>>>(Wp, WPT_OFF, HP, DH);

  // Q/K/V^T for all 32 (b,h)
  qkv_gemm<<<dim3(DH / 128, S_LEN / 128, 3 * NBH), 256, 0, stream>>>(bq, bk, bv);

  // attention in chunks of 8 heads (P chunk = 64 MiB, L3-resident)
  for (int c0 = 0; c0 < NBH; c0 += 8) {
    zero_lsum<<<dim3(16), 256, 0, stream>>>();
    scores_kernel<<<dim3(S_LEN / 128, S_LEN / 128, 8), 256, 0, stream>>>(msk, c0);
    pv_kernel<<<dim3(DH / 128, S_LEN / 128, 8), 256, 0, stream>>>(c0);
  }

  // final projection (fp32 out)
  proj_kernel<<<dim3(DH / 128, (NBAT * S_LEN) / 128), 256, 0, stream>>>(bp, out);
}

// Round 11
// 1014.239 us; speedup vs baseline: 1.0236x; 1.0019x over previous
//
#include <hip/hip_runtime.h>
#include <hip/hip_bf16.h>
#include <cstdint>
#include <cstddef>

typedef unsigned short ushort_t;
typedef __bf16 bf16x8 __attribute__((ext_vector_type(8)));
typedef float floatx4 __attribute__((ext_vector_type(4)));

#define S_LEN 2048
#define DIN   512
#define DH    512
#define NHEAD 8
#define NBAT  4
#define NBH   32
#define HP    4096   // NHEAD*DH

// ---------- static device workspace ----------
#define MiB (1024ull * 1024ull)
#define WQT_OFF   (0ull)           //  4 MiB  WqT [8][512e][512d] bf16
#define WKT_OFF   (4ull  * MiB)    //  4 MiB
#define WVT_OFF   (8ull  * MiB)    //  4 MiB
#define WPT_OFF   (12ull * MiB)    //  4 MiB  WpT [512][4096] bf16
#define XBF_OFF   (16ull * MiB)    //  8 MiB  x bf16 [4][2048][512]
#define Q_OFF     (24ull * MiB)    // 64 MiB  [32][2048][512] bf16
#define K_OFF     (88ull * MiB)    // 64 MiB
#define VT_OFF    (152ull * MiB)   // 64 MiB  [32][512][2048] bf16
#define O_OFF     (216ull * MiB)   // 64 MiB  [4][2048][4096] bf16 (cat)
#define LSUM_OFF  (280ull * MiB)   // 64 KiB  fp32 [8][2048]
#define P_OFF     (281ull * MiB)   // 64 MiB  [8][2048][2048] bf16
#define WS_BYTES  (346ull * MiB)

__device__ __align__(256) unsigned char g_ws[WS_BYTES];

// ---------- helpers ----------
__device__ __forceinline__ ushort_t f2bf(float f) {
  union { float f; uint32_t u; } v; v.f = f;
  uint32_t r = v.u + 0x7fffu + ((v.u >> 16) & 1u);
  return (ushort_t)(r >> 16);
}

typedef __attribute__((address_space(3))) uint32_t lds_uint;
typedef __attribute__((address_space(1))) const uint32_t glb_uint;

__device__ __forceinline__ void async16(void* lds, const void* g) {
  __builtin_amdgcn_global_load_lds((glb_uint*)g, (lds_uint*)lds, 16, 0, 0);
}

// ---------- GEMM core: C[128x128] = A[128xK] * Bt[128xK]^T, bf16, fp32 acc ----
// block = 256 threads (4 waves, 2x2), each wave 64x64 via 4x4 16x16x32 MFMAs.
// SINGLE-BARRIER DOUBLE-BUFFERED K-loop (BK=32):
//   stage(0); loop k: __syncthreads(); stage(k+1 -> other buf); compute(k)
// The barrier's vmcnt(0) drains loads issued a full compute-phase earlier
// (latency hidden by window k-1's MFMAs); DMA for k+1 flies during compute(k).
// Barrier also orders: all waves' ds_reads of window k-1 retire before the
// k+1 DMA overwrites that buffer (lgkmcnt(0)+s_barrier).
// As/Bs are each [2][128][32] bf16 (2 x 8 KiB buffers).
__device__ __forceinline__ void gemm_core(
    const ushort_t* __restrict__ A, const ushort_t* __restrict__ Bt,
    int lda, int ldb, int kdim,
    ushort_t* As, ushort_t* Bs, floatx4 acc[4][4])
{
  const int t = threadIdx.x;
  const int w = t >> 6;
  const int l = t & 63;
  const int wrow = w >> 1, wcol = w & 1;
  const int l15 = l & 15, lq = l >> 4;

  const ushort_t* gA = A + (size_t)(t >> 2) * lda + (t & 3) * 8;
  const ushort_t* gB = Bt + (size_t)(t >> 2) * ldb + (t & 3) * 8;
  const size_t strideA = (size_t)64 * lda;
  const size_t strideB = (size_t)64 * ldb;
  char* ldsA0 = (char*)As + w * 1024;   // wave-uniform LDS base, buffer 0
  char* ldsB0 = (char*)Bs + w * 1024;

  // prologue: stage window 0 into buffer 0
  async16(ldsA0,        gA);
  async16(ldsA0 + 4096, gA + strideA);
  async16(ldsB0,        gB);
  async16(ldsB0 + 4096, gB + strideB);

#pragma unroll
  for (int i = 0; i < 4; ++i)
#pragma unroll
    for (int j = 0; j < 4; ++j)
      acc[i][j] = (floatx4){0.f, 0.f, 0.f, 0.f};

  const int nwin = kdim >> 5;
#pragma unroll 1
  for (int k = 0; k < nwin; ++k) {
    __syncthreads();   // drains window k DMA (old) + prior ds_reads; syncs waves
    const int cur = k & 1;
    if (k + 1 < nwin) {
      const int nxt = cur ^ 1;
      const ushort_t* gA1 = gA + (size_t)(k + 1) * 32;
      const ushort_t* gB1 = gB + (size_t)(k + 1) * 32;
      char* ldsA1 = ldsA0 + nxt * 8192;
      char* ldsB1 = ldsB0 + nxt * 8192;
      async16(ldsA1,        gA1);
      async16(ldsA1 + 4096, gA1 + strideA);
      async16(ldsB1,        gB1);
      async16(ldsB1 + 4096, gB1 + strideB);
    }
    const ushort_t* rdA = As + cur * 4096 + (wrow * 64 + l15) * 32 + lq * 8;
    const ushort_t* rdB = Bs + cur * 4096 + (wcol * 64 + l15) * 32 + lq * 8;

    bf16x8 af[4], bfr[4];
#pragma unroll
    for (int i = 0; i < 4; ++i) af[i] = *(const bf16x8*)(rdA + i * 512);
#pragma unroll
    for (int j = 0; j < 4; ++j) bfr[j] = *(const bf16x8*)(rdB + j * 512);
#pragma unroll
    for (int i = 0; i < 4; ++i)
#pragma unroll
      for (int j = 0; j < 4; ++j)
        acc[i][j] = __builtin_amdgcn_mfma_f32_16x16x32_bf16(af[i], bfr[j], acc[i][j], 0, 0, 0);
  }
}

// ---------- fp32 -> bf16 bulk convert into g_ws ----------
__global__ __launch_bounds__(256) void convert_f32_bf16(
    const float* __restrict__ src, size_t dstOff, int n)
{
  ushort_t* dst = (ushort_t*)(g_ws + dstOff);
  int i = (blockIdx.x * 256 + threadIdx.x) * 4;
  if (i >= n) return;
  float4 v = *(const float4*)(src + i);
  ushort_t o[4] = {f2bf(v.x), f2bf(v.y), f2bf(v.z), f2bf(v.w)};
  *(uint2*)(dst + i) = *(const uint2*)o;
}

// ---------- fp32 [R][C] -> bf16 [C][R] transpose into g_ws, batched over z ----
__global__ __launch_bounds__(256) void transpose_f32_bf16(
    const float* __restrict__ src, size_t dstOff, int R, int C)
{
  __shared__ ushort_t tile[32][33];
  ushort_t* dst = (ushort_t*)(g_ws + dstOff) + (size_t)blockIdx.z * R * C;
  src += (size_t)blockIdx.z * R * C;
  int r0 = blockIdx.y * 32, c0 = blockIdx.x * 32;
  int tx = threadIdx.x & 31, ty = threadIdx.x >> 5;
  for (int i = ty; i < 32; i += 8)
    tile[i][tx] = f2bf(src[(size_t)(r0 + i) * C + (c0 + tx)]);
  __syncthreads();
  for (int i = ty; i < 32; i += 8)
    dst[(size_t)(c0 + i) * R + (r0 + tx)] = tile[tx][i];
}

// ---------- zero lsum (64 KiB) ----------
__global__ __launch_bounds__(256) void zero_lsum()
{
  float* lsum = (float*)(g_ws + LSUM_OFF);
  int i = (blockIdx.x * 256 + threadIdx.x) * 4;
  *(float4*)(lsum + i) = (float4){0.f, 0.f, 0.f, 0.f};
}

// ---------- QKV projection, all batches/heads: z in [0,96) ----------
__global__ __launch_bounds__(256) void qkv_gemm(
    const float* __restrict__ bq, const float* __restrict__ bk,
    const float* __restrict__ bv)
{
  __shared__ __align__(16) ushort_t As[2 * 128 * 32], Bs[2 * 128 * 32];
  const int z = blockIdx.z;
  const int bh = z & 31, qkv = z >> 5, b = bh >> 3, h = bh & 7;
  const size_t wOff = (qkv == 0) ? WQT_OFF : (qkv == 1) ? WKT_OFF : WVT_OFF;
  const float* bias = ((qkv == 0) ? bq : (qkv == 1) ? bk : bv) + h * DH;
  const int tileM = blockIdx.y * 128, tileN = blockIdx.x * 128;

  const ushort_t* A  = (const ushort_t*)(g_ws + XBF_OFF)
                       + ((size_t)b * S_LEN + tileM) * DIN;
  const ushort_t* Bt = (const ushort_t*)(g_ws + wOff)
                       + ((size_t)h * DH + tileN) * DIN;
  floatx4 acc[4][4];
  gemm_core(A, Bt, DIN, DIN, DIN, As, Bs, acc);

  ushort_t* Qb = (ushort_t*)(g_ws + Q_OFF);
  ushort_t* Kb = (ushort_t*)(g_ws + K_OFF);
  ushort_t* VT = (ushort_t*)(g_ws + VT_OFF);
  const int t = threadIdx.x, w = t >> 6, l = t & 63;
  const int wrow = w >> 1, wcol = w & 1, l15 = l & 15, lq = l >> 4;
#pragma unroll
  for (int j = 0; j < 4; ++j) {
    const int n = tileN + wcol * 64 + j * 16 + l15;
    const float bsn = bias[n];
#pragma unroll
    for (int i = 0; i < 4; ++i) {
#pragma unroll
      for (int r = 0; r < 4; ++r) {
        const int m = tileM + wrow * 64 + i * 16 + lq * 4 + r;
        const float v = acc[i][j][r] + bsn;
        if (qkv == 0)      Qb[((size_t)bh * S_LEN + m) * DH + n] = f2bf(v);
        else if (qkv == 1) Kb[((size_t)bh * S_LEN + m) * DH + n] = f2bf(v);
        else               VT[((size_t)bh * DH + n) * S_LEN + m] = f2bf(v);
      }
    }
  }
}

// ---------- scores + masked exp + fused row-sum for head chunk [c0, c0+8) ----
__global__ __launch_bounds__(256) void scores_kernel(
    const int* __restrict__ mask, int c0)
{
  __shared__ __align__(16) ushort_t As[2 * 128 * 32], Bs[2 * 128 * 32];
  const int hl = blockIdx.z, bh = c0 + hl, b = bh >> 3;
  const int tileM = blockIdx.y * 128, tileN = blockIdx.x * 128;

  const ushort_t* A  = (const ushort_t*)(g_ws + Q_OFF)
                       + ((size_t)bh * S_LEN + tileM) * DH;
  const ushort_t* Bt = (const ushort_t*)(g_ws + K_OFF)
                       + ((size_t)bh * S_LEN + tileN) * DH;
  floatx4 acc[4][4];
  gemm_core(A, Bt, DH, DH, DH, As, Bs, acc);

  const float scale = 0.04419417382415922f;  // 1/sqrt(512)
  const int t = threadIdx.x, w = t >> 6, l = t & 63;
  const int wrow = w >> 1, wcol = w & 1, l15 = l & 15, lq = l >> 4;
  ushort_t* Pp = (ushort_t*)(g_ws + P_OFF) + (size_t)hl * S_LEN * S_LEN;
  const int* mask_b = mask + (size_t)b * S_LEN;
  float* lsum = (float*)(g_ws + LSUM_OFF);

  float rsum[4][4];
#pragma unroll
  for (int i = 0; i < 4; ++i)
#pragma unroll
    for (int r = 0; r < 4; ++r) rsum[i][r] = 0.f;

#pragma unroll
  for (int j = 0; j < 4; ++j) {
    const int n = tileN + wcol * 64 + j * 16 + l15;
    const int mv = mask_b[n];
#pragma unroll
    for (int i = 0; i < 4; ++i) {
#pragma unroll
      for (int r = 0; r < 4; ++r) {
        const int m = tileM + wrow * 64 + i * 16 + lq * 4 + r;
        float s = fminf(acc[i][j][r] * scale, 30.f);  // clamp: no inf possible
        const float p = mv ? __expf(s) : 0.f;
        rsum[i][r] += p;
        Pp[(size_t)m * S_LEN + n] = f2bf(p);
      }
    }
  }
  // reduce across the 16 lanes sharing each row, one atomic per (row, wave)
#pragma unroll
  for (int i = 0; i < 4; ++i) {
#pragma unroll
    for (int r = 0; r < 4; ++r) {
      float v = rsum[i][r];
      v += __shfl_xor(v, 1);
      v += __shfl_xor(v, 2);
      v += __shfl_xor(v, 4);
      v += __shfl_xor(v, 8);
      if (l15 == 0) {
        const int m = tileM + wrow * 64 + i * 16 + lq * 4 + r;
        atomicAdd(&lsum[(size_t)hl * S_LEN + m], v);
      }
    }
  }
}

// ---------- P*V, divide by rowsum, store cat-layout O ----------
__global__ __launch_bounds__(256) void pv_kernel(int c0)
{
  __shared__ __align__(16) ushort_t As[2 * 128 * 32], Bs[2 * 128 * 32];
  const int hl = blockIdx.z, bh = c0 + hl, b = bh >> 3, h = bh & 7;
  const int tileM = blockIdx.y * 128, tileN = blockIdx.x * 128;

  const ushort_t* A  = (const ushort_t*)(g_ws + P_OFF)
                       + (size_t)hl * S_LEN * S_LEN + (size_t)tileM * S_LEN;
  const ushort_t* Bt = (const ushort_t*)(g_ws + VT_OFF)
                       + ((size_t)bh * DH + tileN) * S_LEN;
  floatx4 acc[4][4];
  gemm_core(A, Bt, S_LEN, S_LEN, S_LEN, As, Bs, acc);

  const float* lsum = (const float*)(g_ws + LSUM_OFF);
  ushort_t* Ob = (ushort_t*)(g_ws + O_OFF);
  const int t = threadIdx.x, w = t >> 6, l = t & 63;
  const int wrow = w >> 1, wcol = w & 1, l15 = l & 15, lq = l >> 4;
#pragma unroll
  for (int i = 0; i < 4; ++i) {
#pragma unroll
    for (int r = 0; r < 4; ++r) {
      const int m = tileM + wrow * 64 + i * 16 + lq * 4 + r;
      const float lv = lsum[(size_t)hl * S_LEN + m];
      const float inv = (lv > 1e-20f) ? 1.0f / lv : 0.f;  // no inf possible
#pragma unroll
      for (int j = 0; j < 4; ++j) {
        const int n = tileN + wcol * 64 + j * 16 + l15;
        Ob[((size_t)b * S_LEN + m) * HP + h * DH + n] = f2bf(acc[i][j][r] * inv);
      }
    }
  }
}

// ---------- out projection: out_f32[8192][512] = Ob[8192][4096]*WpT^T + bp ----
__global__ __launch_bounds__(256) void proj_kernel(
    const float* __restrict__ bp, float* __restrict__ out)
{
  __shared__ __align__(16) ushort_t As[2 * 128 * 32], Bs[2 * 128 * 32];
  const int tileM = blockIdx.y * 128, tileN = blockIdx.x * 128;

  const ushort_t* A  = (const ushort_t*)(g_ws + O_OFF) + (size_t)tileM * HP;
  const ushort_t* Bt = (const ushort_t*)(g_ws + WPT_OFF) + (size_t)tileN * HP;
  floatx4 acc[4][4];
  gemm_core(A, Bt, HP, HP, HP, As, Bs, acc);

  const int t = threadIdx.x, w = t >> 6, l = t & 63;
  const int wrow = w >> 1, wcol = w & 1, l15 = l & 15, lq = l >> 4;
#pragma unroll
  for (int j = 0; j < 4; ++j) {
    const int n = tileN + wcol * 64 + j * 16 + l15;
    const float bsn = bp[n];
#pragma unroll
    for (int i = 0; i < 4; ++i) {
#pragma unroll
      for (int r = 0; r < 4; ++r) {
        const int m = tileM + wrow * 64 + i * 16 + lq * 4 + r;
        out[(size_t)m * DH + n] = acc[i][j][r] + bsn;   // fp32 store
      }
    }
  }
}

// ---------- host ----------
extern "C" void kernel_launch(void* const* d_in, const int* in_sizes, int n_in,
                              void* d_out, int out_size, void* d_ws, size_t ws_size,
                              hipStream_t stream) {
  // Inputs fp32 (mask int32); OUTPUT fp32.
  const float* x  = (const float*)d_in[0];
  const int*   msk= (const int*)d_in[1];
  const float* Wq = (const float*)d_in[2];
  const float* bq = (const float*)d_in[3];
  const float* Wk = (const float*)d_in[4];
  const float* bk = (const float*)d_in[5];
  const float* Wv = (const float*)d_in[6];
  const float* bv = (const float*)d_in[7];
  const float* Wp = (const float*)d_in[8];
  const float* bp = (const float*)d_in[9];
  float* out = (float*)d_out;

  // x -> bf16 (all batches)
  convert_f32_bf16<<<dim3(NBAT * S_LEN * DIN / 1024), 256, 0, stream>>>(
      x, XBF_OFF, NBAT * S_LEN * DIN);

  // weight transposes (fp32 -> bf16)
  transpose_f32_bf16<<<dim3(16, 16, NHEAD), 256, 0, stream>>>(Wq, WQT_OFF, DIN, DH);
  transpose_f32_bf16<<<dim3(16, 16, NHEAD), 256, 0, stream>>>(Wk, WKT_OFF, DIN, DH);
  transpose_f32_bf16<<<dim3(16, 16, NHEAD), 256, 0, stream>>>(Wv, WVT_OFF, DIN, DH);
  transpose_f32_bf16<<<dim3(16, 128, 1),    256, 0, stream>>>(Wp, WPT_OFF, HP, DH);

  // Q/K/V^T for all 32 (b,h)
  qkv_gemm<<<dim3(DH / 128, S_LEN / 128, 3 * NBH), 256, 0, stream>>>(bq, bk, bv);

  // attention in chunks of 8 heads (P chunk = 64 MiB, L3-resident)
  for (int c0 = 0; c0 < NBH; c0 += 8) {
    zero_lsum<<<dim3(16), 256, 0, stream>>>();
    scores_kernel<<<dim3(S_LEN / 128, S_LEN / 128, 8), 256, 0, stream>>>(msk, c0);
    pv_kernel<<<dim3(DH / 128, S_LEN / 128, 8), 256, 0, stream>>>(c0);
  }

  // final projection (fp32 out)
  proj_kernel<<<dim3(DH / 128, (NBAT * S_LEN) / 128), 256, 0, stream>>>(bp, out);
}